// Round 2
// baseline (379.871 us; speedup 1.0000x reference)
//
#include <hip/hip_runtime.h>

#define BINS 10
#define REPL 64        // one histogram replica per lane -> no intra-wave same-address atomics
#define RSTRIDE 11     // odd word stride: lane L, bin b -> bank (11L+b)%32; worst case 2-way (free)
#define NWORDS (REPL * RSTRIDE)

// Per-element: bin + BCE partial, accumulate into this lane's private LDS
// replica via non-returning ds_add atomics (atomics needed only because the
// block's 4 waves share the 64 replicas).
__device__ __forceinline__ void accum_elem(float xx, float tt,
                                           float* __restrict__ myrow,
                                           unsigned* __restrict__ myrowc) {
    float g = fabsf(xx - tt);
    // reference: floor(g * (10 - 1e-4)); g < 1 strictly (x in (1e-4,1-1e-4),
    // t in [0,1)) so g*9.9999 < 10 -> b in [0,9], no clamp needed.
    int b = (int)(g * 9.9999f);
    float om = 1.0f - xx;
    float l1 = __logf(xx);
    float l2 = __logf(om);
    // s = t*log(x) + (1-t)*log(1-x); loss = -s, negation applied in finalize
    float s = __builtin_fmaf(tt, l1 - l2, l2);
    atomicAdd(&myrow[b], s);     // ds_add_f32 (no return)
    atomicAdd(&myrowc[b], 1u);   // ds_add_u32 (no return)
}

__global__ __launch_bounds__(256) void ghm_partial(
    const float* __restrict__ x, const float* __restrict__ t,
    float* __restrict__ psum, unsigned* __restrict__ pcnt,
    int n4, long long n_total, int nblocks)
{
    __shared__ float ls[NWORDS];      // replica-major loss sums
    __shared__ unsigned lc[NWORDS];   // replica-major counts

    for (int i = threadIdx.x; i < NWORDS; i += 256) { ls[i] = 0.0f; lc[i] = 0u; }
    __syncthreads();

    const int lane = threadIdx.x & 63;
    float* __restrict__ myrow = &ls[lane * RSTRIDE];
    unsigned* __restrict__ myrowc = &lc[lane * RSTRIDE];

    const float4* __restrict__ x4 = (const float4*)x;
    const float4* __restrict__ t4 = (const float4*)t;
    int tid = blockIdx.x * blockDim.x + threadIdx.x;
    int stride = gridDim.x * blockDim.x;

    for (int i = tid; i < n4; i += stride) {
        float4 xv = x4[i];
        float4 tv = t4[i];
        accum_elem(xv.x, tv.x, myrow, myrowc);
        accum_elem(xv.y, tv.y, myrow, myrowc);
        accum_elem(xv.z, tv.z, myrow, myrowc);
        accum_elem(xv.w, tv.w, myrow, myrowc);
    }
    // scalar tail (N % 4) — low global tids
    long long tail_base = (long long)n4 * 4;
    long long rem = n_total - tail_base;
    if ((long long)tid < rem) {
        accum_elem(x[tail_base + tid], t[tail_base + tid], myrow, myrowc);
    }

    __syncthreads();

    // Wave 0 reduces the 64 replicas: lane r holds replica r's 10 bins,
    // butterfly-reduce across lanes, lane 0 writes bin-major partials.
    if (threadIdx.x < 64) {
        float s[BINS];
        unsigned c[BINS];
#pragma unroll
        for (int b = 0; b < BINS; ++b) {
            s[b] = ls[lane * RSTRIDE + b];
            c[b] = lc[lane * RSTRIDE + b];
        }
#pragma unroll
        for (int b = 0; b < BINS; ++b) {
#pragma unroll
            for (int off = 32; off > 0; off >>= 1) {
                s[b] += __shfl_down(s[b], off, 64);
                c[b] += (unsigned)__shfl_down((int)c[b], off, 64);
            }
        }
        if (lane == 0) {
#pragma unroll
            for (int b = 0; b < BINS; ++b) {
                psum[(size_t)b * nblocks + blockIdx.x] = s[b];
                pcnt[(size_t)b * nblocks + blockIdx.x] = c[b];
            }
        }
    }
}

// Single block: bin-major coalesced reduction of partials, beta, weighted sum.
__global__ __launch_bounds__(256) void ghm_final(
    const float* __restrict__ psum, const unsigned* __restrict__ pcnt,
    float* __restrict__ out, int nblocks, float Nf)
{
    float bs[BINS];
    unsigned bc[BINS];
#pragma unroll
    for (int b = 0; b < BINS; ++b) {
        float s = 0.0f;
        unsigned c = 0u;
        for (int i = threadIdx.x; i < nblocks; i += 256) {
            s += psum[(size_t)b * nblocks + i];
            c += pcnt[(size_t)b * nblocks + i];
        }
        bs[b] = s;
        bc[b] = c;
    }

#pragma unroll
    for (int b = 0; b < BINS; ++b) {
#pragma unroll
        for (int off = 32; off > 0; off >>= 1) {
            bs[b] += __shfl_down(bs[b], off, 64);
            bc[b] += (unsigned)__shfl_down((int)bc[b], off, 64);
        }
    }

    __shared__ float s_sum[4][BINS];
    __shared__ unsigned s_cnt[4][BINS];
    int lane = threadIdx.x & 63;
    int wv = threadIdx.x >> 6;
    if (lane == 0) {
#pragma unroll
        for (int b = 0; b < BINS; ++b) { s_sum[wv][b] = bs[b]; s_cnt[wv][b] = bc[b]; }
    }
    __syncthreads();

    if (threadIdx.x == 0) {
        float nonempty = 0.0f;
        float tot_s[BINS];
        unsigned tot_c[BINS];
#pragma unroll
        for (int b = 0; b < BINS; ++b) {
            float s = 0.0f;
            unsigned c = 0u;
#pragma unroll
            for (int w = 0; w < 4; ++w) { s += s_sum[w][b]; c += s_cnt[w][b]; }
            tot_s[b] = s;
            tot_c[b] = c;
            nonempty += (c > 0u) ? 1.0f : 0.0f;
        }
        float total = 0.0f;
#pragma unroll
        for (int b = 0; b < BINS; ++b) {
            float gd = (float)tot_c[b] * nonempty;
            gd = gd < 1.0f ? 1.0f : gd;        // clip(gd, 1, None)
            total += tot_s[b] * (Nf / gd);     // beta = N/gd
        }
        out[0] = -total / Nf;  // undo deferred negation, take mean
    }
}

extern "C" void kernel_launch(void* const* d_in, const int* in_sizes, int n_in,
                              void* d_out, int out_size, void* d_ws, size_t ws_size,
                              hipStream_t stream) {
    const float* x = (const float*)d_in[0];
    const float* t = (const float*)d_in[1];
    float* out = (float*)d_out;

    long long N = (long long)in_sizes[0];
    int n4 = (int)(N / 4);

    // 2048 blocks x 256 thr = 8192 waves = 32/CU (max occupancy for latency hiding)
    int nblocks = 2048;
    size_t per_block = (size_t)BINS * (sizeof(float) + sizeof(unsigned)); // 80 B
    size_t maxb = ws_size / per_block;
    if ((size_t)nblocks > maxb) nblocks = (int)maxb;
    if (nblocks < 1) nblocks = 1;

    float* psum = (float*)d_ws;                                   // [BINS][nblocks]
    unsigned* pcnt = (unsigned*)(psum + (size_t)BINS * nblocks);  // [BINS][nblocks]

    ghm_partial<<<nblocks, 256, 0, stream>>>(x, t, psum, pcnt, n4, N, nblocks);
    ghm_final<<<1, 256, 0, stream>>>(psum, pcnt, out, nblocks, (float)N);
}

// Round 3
// 286.881 us; speedup vs baseline: 1.3241x; 1.3241x over previous
//
#include <hip/hip_runtime.h>

#define BINS 10
#define NTHR 9   // thresholds j = 1..9: bin >= j  <=>  y >= (float)j

// Cumulative-threshold accumulation: shares one v_cmp per threshold between
// the loss sum (cndmask+add) and the count (addc). No bin cvt, no clamp.
// s = t*log2(x) + (1-t)*log2(1-x)  (negative); scaled by -ln2 in finalize.
__device__ __forceinline__ void accum_elem(float xx, float tt, float sc_mul,
                                           float* __restrict__ S,   // [NTHR] cumulative loss sums
                                           unsigned* __restrict__ C,// [NTHR] cumulative counts
                                           float& s_total) {
    float y = fabsf(xx - tt) * sc_mul;      // y = g * 9.9999f (rounded once, like ref)
    float om = 1.0f - xx;
    float l1 = __log2f(xx);
    float l2 = __log2f(om);
    float s = __builtin_fmaf(tt, l1 - l2, l2);
    s_total += s;
#pragma unroll
    for (int j = 0; j < NTHR; ++j) {
        bool p = (y >= (float)(j + 1));     // v_cmp_le_f32 -> vcc
        S[j] += p ? s : 0.0f;               // v_cndmask + v_add_f32
        C[j] += p ? 1u : 0u;                // v_addc_co_u32 (carry = vcc)
    }
}

__global__ __launch_bounds__(256) void ghm_partial(
    const float* __restrict__ x, const float* __restrict__ t,
    float* __restrict__ psum, unsigned* __restrict__ pcnt,
    int n4, long long n_total, int nblocks)
{
    float S[NTHR];
    unsigned C[NTHR];
    float s_total = 0.0f;
#pragma unroll
    for (int j = 0; j < NTHR; ++j) { S[j] = 0.0f; C[j] = 0u; }

    const float sc_mul = 9.9999f;
    const float4* __restrict__ x4 = (const float4*)x;
    const float4* __restrict__ t4 = (const float4*)t;
    int tid = blockIdx.x * blockDim.x + threadIdx.x;
    int stride = gridDim.x * blockDim.x;

    // grid-stride with depth-1 register prefetch: next iteration's 32 B are
    // in flight while the current 4 elements are processed.
    int i = tid;
    if (i < n4) {
        float4 cx = x4[i];
        float4 ct = t4[i];
        for (;;) {
            int nx = i + stride;
            bool more = nx < n4;
            float4 px, pt;
            if (more) { px = x4[nx]; pt = t4[nx]; }
            accum_elem(cx.x, ct.x, sc_mul, S, C, s_total);
            accum_elem(cx.y, ct.y, sc_mul, S, C, s_total);
            accum_elem(cx.z, ct.z, sc_mul, S, C, s_total);
            accum_elem(cx.w, ct.w, sc_mul, S, C, s_total);
            if (!more) break;
            cx = px; ct = pt; i = nx;
        }
    }
    // scalar tail (N % 4) — low global tids
    long long tail_base = (long long)n4 * 4;
    long long rem = n_total - tail_base;
    if ((long long)tid < rem) {
        accum_elem(x[tail_base + tid], t[tail_base + tid], sc_mul, S, C, s_total);
    }

    // wave(64) shuffle reduction: 1 total + 9 cumulative sums + 9 counts
#pragma unroll
    for (int off = 32; off > 0; off >>= 1) s_total += __shfl_down(s_total, off, 64);
#pragma unroll
    for (int j = 0; j < NTHR; ++j) {
#pragma unroll
        for (int off = 32; off > 0; off >>= 1) {
            S[j] += __shfl_down(S[j], off, 64);
            C[j] += (unsigned)__shfl_down((int)C[j], off, 64);
        }
    }

    __shared__ float s_sum[4][NTHR + 1];
    __shared__ unsigned s_cnt[4][NTHR];
    int lane = threadIdx.x & 63;
    int wv = threadIdx.x >> 6;
    if (lane == 0) {
        s_sum[wv][0] = s_total;
#pragma unroll
        for (int j = 0; j < NTHR; ++j) { s_sum[wv][j + 1] = S[j]; s_cnt[wv][j] = C[j]; }
    }
    __syncthreads();
    // rows 0..9 of psum: row 0 = S_total, rows 1..9 = Sc_j ; pcnt rows 0..8 = C_j
    if (threadIdx.x < NTHR + 1) {
        int r = threadIdx.x;
        float s = 0.0f;
#pragma unroll
        for (int w = 0; w < 4; ++w) s += s_sum[w][r];
        psum[(size_t)r * nblocks + blockIdx.x] = s;
        if (r < NTHR) {
            unsigned c = 0u;
#pragma unroll
            for (int w = 0; w < 4; ++w) c += s_cnt[w][r];
            pcnt[(size_t)r * nblocks + blockIdx.x] = c;
        }
    }
}

// Single block: coalesced bin-major reduction, difference cumulative -> bins,
// beta, weighted total.
__global__ __launch_bounds__(256) void ghm_final(
    const float* __restrict__ psum, const unsigned* __restrict__ pcnt,
    float* __restrict__ out, int nblocks, float Nf, long long N)
{
    float rs[NTHR + 1];
    unsigned rc[NTHR];
#pragma unroll
    for (int r = 0; r < NTHR + 1; ++r) rs[r] = 0.0f;
#pragma unroll
    for (int r = 0; r < NTHR; ++r) rc[r] = 0u;

    for (int i = threadIdx.x; i < nblocks; i += 256) {
#pragma unroll
        for (int r = 0; r < NTHR + 1; ++r) rs[r] += psum[(size_t)r * nblocks + i];
#pragma unroll
        for (int r = 0; r < NTHR; ++r) rc[r] += pcnt[(size_t)r * nblocks + i];
    }

#pragma unroll
    for (int r = 0; r < NTHR + 1; ++r) {
#pragma unroll
        for (int off = 32; off > 0; off >>= 1) rs[r] += __shfl_down(rs[r], off, 64);
    }
#pragma unroll
    for (int r = 0; r < NTHR; ++r) {
#pragma unroll
        for (int off = 32; off > 0; off >>= 1) rc[r] += (unsigned)__shfl_down((int)rc[r], off, 64);
    }

    __shared__ float s_sum[4][NTHR + 1];
    __shared__ unsigned s_cnt[4][NTHR];
    int lane = threadIdx.x & 63;
    int wv = threadIdx.x >> 6;
    if (lane == 0) {
#pragma unroll
        for (int r = 0; r < NTHR + 1; ++r) s_sum[wv][r] = rs[r];
#pragma unroll
        for (int r = 0; r < NTHR; ++r) s_cnt[wv][r] = rc[r];
    }
    __syncthreads();

    if (threadIdx.x == 0) {
        float Sc[BINS + 1];      // cumulative sums: Sc[0]=total, Sc[10]=0
        float Cc[BINS + 1];      // cumulative counts: Cc[0]=N, Cc[10]=0
#pragma unroll
        for (int r = 0; r < NTHR + 1; ++r) {
            float s = 0.0f;
#pragma unroll
            for (int w = 0; w < 4; ++w) s += s_sum[w][r];
            Sc[r] = s;
        }
        Sc[BINS] = 0.0f;
        Cc[0] = (float)N;
#pragma unroll
        for (int r = 0; r < NTHR; ++r) {
            unsigned c = 0u;
#pragma unroll
            for (int w = 0; w < 4; ++w) c += s_cnt[w][r];
            Cc[r + 1] = (float)c;
        }
        Cc[BINS] = 0.0f;

        float cnt[BINS], sb[BINS];
        float nonempty = 0.0f;
#pragma unroll
        for (int b = 0; b < BINS; ++b) {
            cnt[b] = Cc[b] - Cc[b + 1];     // exact (integers in fp32 range per diff)
            sb[b] = Sc[b] - Sc[b + 1];
            nonempty += (cnt[b] > 0.0f) ? 1.0f : 0.0f;
        }
        float total = 0.0f;
#pragma unroll
        for (int b = 0; b < BINS; ++b) {
            float gd = cnt[b] * nonempty;
            gd = gd < 1.0f ? 1.0f : gd;      // clip(gd, 1, None)
            total += sb[b] * (Nf / gd);      // beta = N/gd
        }
        // s was t*log2(x)+(1-t)*log2(1-x); loss = -ln2 * s; mean over N
        const float LN2 = 0.69314718055994530942f;
        out[0] = -LN2 * total / Nf;
    }
}

extern "C" void kernel_launch(void* const* d_in, const int* in_sizes, int n_in,
                              void* d_out, int out_size, void* d_ws, size_t ws_size,
                              hipStream_t stream) {
    const float* x = (const float*)d_in[0];
    const float* t = (const float*)d_in[1];
    float* out = (float*)d_out;

    long long N = (long long)in_sizes[0];
    int n4 = (int)(N / 4);

    // 2048 blocks x 256 thr = 8192 waves = 32/CU
    int nblocks = 2048;
    size_t per_block = (size_t)(NTHR + 1) * sizeof(float) + (size_t)NTHR * sizeof(unsigned); // 76 B
    size_t maxb = ws_size / per_block;
    if ((size_t)nblocks > maxb) nblocks = (int)maxb;
    if (nblocks < 1) nblocks = 1;

    float* psum = (float*)d_ws;                                         // [10][nblocks]
    unsigned* pcnt = (unsigned*)(psum + (size_t)(NTHR + 1) * nblocks);  // [9][nblocks]

    ghm_partial<<<nblocks, 256, 0, stream>>>(x, t, psum, pcnt, n4, N, nblocks);
    ghm_final<<<1, 256, 0, stream>>>(psum, pcnt, out, nblocks, (float)N, N);
}